// Round 8
// baseline (218.466 us; speedup 1.0000x reference)
//
#include <hip/hip_runtime.h>

// ---------------------------------------------------------------------------
// TTLinear on MI355X — round 7.
//   k_cvt8/k_cvtw: X, {t_q,W1,W2} -> bf16
//   k_q8 : Q = X @ t_q^T   256x256 8-phase counted-vmcnt. RACE-FIXED:
//          every staged region's last read is in a STRICTLY EARLIER phase
//          (barrier-separated); per-group vmcnt(4) proves landing.
//          Group G_j (slot u=j&1): p0:STA(u^1,1,j+1) p1:STB(u^1,1,j+1)
//                                  p2:STA(u,0,j+2)   p3:STB(u,0,j+2)+vmcnt(4)
//   k_mlp: out = Q + gelu(Q@W1^T+b1)@W2^T + b2  (R5-proven fused MLP,
//          h2 kept in LDS; measured ~12us better than split l1+l2)
// ---------------------------------------------------------------------------

#define DD      1024
#define HH      1024
#define H4      256
#define MROWS   32768          // T*N = 128*256

typedef unsigned short u16;
typedef __bf16 bf16x8 __attribute__((ext_vector_type(8)));
typedef float  f32x4  __attribute__((ext_vector_type(4)));

__device__ __forceinline__ u16 f2b(float x) {            // fp32 -> bf16 (RNE)
  unsigned u = __builtin_bit_cast(unsigned, x);
  unsigned r = (u + 0x7fffu + ((u >> 16) & 1u)) >> 16;
  return (u16)r;
}
__device__ __forceinline__ float b2f(u16 x) {
  return __builtin_bit_cast(float, ((unsigned)x) << 16);
}

__device__ __forceinline__ void gload16(const u16* g, u16* l) {
  __builtin_amdgcn_global_load_lds(
      (const __attribute__((address_space(1))) unsigned int*)g,
      (__attribute__((address_space(3))) unsigned int*)l, 16, 0, 0);
}

// ---------------------------------------------------------------------------
// fp32 -> bf16 bulk converts
// ---------------------------------------------------------------------------
__device__ __forceinline__ void cvt8_at(u16* dst, const float* src, size_t i) {
  const float4* s = (const float4*)(src + i);
  const float4 f0 = s[0], f1 = s[1];
  uint4 pk;
  pk.x = (unsigned)f2b(f0.x) | ((unsigned)f2b(f0.y) << 16);
  pk.y = (unsigned)f2b(f0.z) | ((unsigned)f2b(f0.w) << 16);
  pk.z = (unsigned)f2b(f1.x) | ((unsigned)f2b(f1.y) << 16);
  pk.w = (unsigned)f2b(f1.z) | ((unsigned)f2b(f1.w) << 16);
  *(uint4*)(dst + i) = pk;
}

__global__ __launch_bounds__(256) void k_cvt8(u16* __restrict__ dst,
                                              const float* __restrict__ src) {
  cvt8_at(dst, src, ((size_t)blockIdx.x * 256 + threadIdx.x) * 8);
}

// weights: blocks [0,512) -> t_q, [512,640) -> W1, [640,768) -> W2
__global__ __launch_bounds__(256) void k_cvtw(
    const float* __restrict__ tq, const float* __restrict__ W1,
    const float* __restrict__ W2, u16* __restrict__ tqb,
    u16* __restrict__ W1b, u16* __restrict__ W2b) {
  const int b = blockIdx.x;
  if (b < 512)      cvt8_at(tqb, tq, ((size_t)b * 256 + threadIdx.x) * 8);
  else if (b < 640) cvt8_at(W1b, W1, ((size_t)(b - 512) * 256 + threadIdx.x) * 8);
  else              cvt8_at(W2b, W2, ((size_t)(b - 640) * 256 + threadIdx.x) * 8);
}

// ---------------------------------------------------------------------------
// k_q8: 256x256-tile, BK=64, 8 waves (2Mx4N), 8-phase counted-vmcnt.
// LDS: sA/sB x 2 slots [256][64] bf16 linear, source-preswizzled
// (LDS[r][b] = G[r][b ^ (r&7)], r&7 == srow by construction).
// Reads in group (slot u): A0@p0,p1  A1@p2,p3  B0@p0,p2  B1@p1,p3.
// ---------------------------------------------------------------------------
#define STA(s, h, kt)                                                         \
  { gload16(Ag + (size_t)((h)*128      + w*8 + srow) * 1024 + (kt)*64 + scol, \
            &sA[s][((h)*128      + w*8) * 64]);                               \
    gload16(Ag + (size_t)((h)*128 + 64 + w*8 + srow) * 1024 + (kt)*64 + scol, \
            &sA[s][((h)*128 + 64 + w*8) * 64]); }

#define STB(s, h, kt)                                                         \
  { gload16(Bg + (size_t)((h)*128      + w*8 + srow) * 1024 + (kt)*64 + scol, \
            &sB[s][((h)*128      + w*8) * 64]);                               \
    gload16(Bg + (size_t)((h)*128 + 64 + w*8 + srow) * 1024 + (kt)*64 + scol, \
            &sB[s][((h)*128 + 64 + w*8) * 64]); }

#define PH(s, MH, NH, STG, DOVM)                                              \
  {                                                                           \
    bf16x8 af[4][2], bg[2][2];                                                \
    _Pragma("unroll")                                                         \
    for (int mi = 0; mi < 4; ++mi) {                                          \
      const int row = (MH)*128 + wm*64 + mi*16 + lr;                          \
      const u16* rp = &sA[s][row * 64];                                       \
      af[mi][0] = *(const bf16x8*)(rp + (((lg    ) ^ (row & 7)) << 3));       \
      af[mi][1] = *(const bf16x8*)(rp + (((lg + 4) ^ (row & 7)) << 3));       \
    }                                                                         \
    _Pragma("unroll")                                                         \
    for (int ni = 0; ni < 2; ++ni) {                                          \
      const int row = (NH)*128 + wn*32 + ni*16 + lr;                          \
      const u16* rp = &sB[s][row * 64];                                       \
      bg[ni][0] = *(const bf16x8*)(rp + (((lg    ) ^ (row & 7)) << 3));       \
      bg[ni][1] = *(const bf16x8*)(rp + (((lg + 4) ^ (row & 7)) << 3));       \
    }                                                                         \
    STG;                                                                      \
    __builtin_amdgcn_sched_barrier(0);                                        \
    __builtin_amdgcn_s_barrier();                                             \
    asm volatile("s_waitcnt lgkmcnt(0)" ::: "memory");                        \
    __builtin_amdgcn_sched_barrier(0);                                        \
    __builtin_amdgcn_s_setprio(1);                                            \
    _Pragma("unroll")                                                         \
    for (int ks = 0; ks < 2; ++ks)                                            \
      _Pragma("unroll")                                                       \
      for (int mi = 0; mi < 4; ++mi)                                          \
        _Pragma("unroll")                                                     \
        for (int ni = 0; ni < 2; ++ni)                                        \
          acc[(MH)*4+mi][(NH)*2+ni] = __builtin_amdgcn_mfma_f32_16x16x32_bf16(\
              af[mi][ks], bg[ni][ks], acc[(MH)*4+mi][(NH)*2+ni], 0, 0, 0);    \
    __builtin_amdgcn_s_setprio(0);                                            \
    __builtin_amdgcn_sched_barrier(0);                                        \
    if (DOVM) asm volatile("s_waitcnt vmcnt(4)" ::: "memory");                \
    __builtin_amdgcn_s_barrier();                                             \
    __builtin_amdgcn_sched_barrier(0);                                        \
  }

// Group G_j, slot u=j&1. Every stage targets a region whose last read is in a
// strictly earlier phase; vmcnt(4) at p3 leaves only p2/p3's 4 loads in
// flight, so all of slot u^1's tile-(j+1) data has LANDED before G_{j+1}.
#define GROUP(u, j)                                                           \
  PH(u, 0, 0, STA(u^1, 1, ((j)+1) & 15), 0)                                   \
  PH(u, 0, 1, STB(u^1, 1, ((j)+1) & 15), 0)                                   \
  PH(u, 1, 0, STA(u,   0, ((j)+2) & 15), 0)                                   \
  PH(u, 1, 1, STB(u,   0, ((j)+2) & 15), 1)

__global__ __launch_bounds__(512, 2) void k_q8(
    const u16* __restrict__ A, const u16* __restrict__ B, u16* __restrict__ C)
{
  __shared__ u16 sA[2][256 * 64];
  __shared__ u16 sB[2][256 * 64];
  const int tid  = threadIdx.x;
  const int m0   = blockIdx.x * 256, n0 = blockIdx.y * 256;
  const int lane = tid & 63, w = tid >> 6;        // 8 waves
  const int wm = w >> 2, wn = w & 3;              // 2M x 4N wave grid
  const int lr = lane & 15, lg = lane >> 4;
  const int srow = lane >> 3;                     // staging row-in-8
  const int scol = ((lane & 7) ^ srow) << 3;      // pre-swizzled src col (u16)
  const u16* Ag = A + (size_t)m0 * 1024;
  const u16* Bg = B + (size_t)n0 * 1024;

  f32x4 acc[8][4];
  #pragma unroll
  for (int i = 0; i < 8; ++i)
    #pragma unroll
    for (int j = 0; j < 4; ++j) { f32x4 z = {0.f, 0.f, 0.f, 0.f}; acc[i][j] = z; }

  // Prologue: slot0 = tile0 complete (8 loads) + slot1 tile1 {A0,B0} (4).
  STA(0, 0, 0); STB(0, 0, 0); STA(0, 1, 0); STB(0, 1, 0);
  STA(1, 0, 1); STB(1, 0, 1);
  asm volatile("s_waitcnt vmcnt(4)" ::: "memory");   // slot0 fully landed
  __builtin_amdgcn_s_barrier();
  __builtin_amdgcn_sched_barrier(0);

  #pragma unroll 1
  for (int t = 0; t < 8; ++t) {
    GROUP(0, 2 * t)
    GROUP(1, 2 * t + 1)
  }
  asm volatile("s_waitcnt vmcnt(0)" ::: "memory");

  #pragma unroll
  for (int im = 0; im < 8; ++im)
    #pragma unroll
    for (int in = 0; in < 4; ++in)
      #pragma unroll
      for (int r = 0; r < 4; ++r) {
        const int grow = m0 + (im >> 2) * 128 + wm * 64 + (im & 3) * 16 + lg * 4 + r;
        const int gcol = n0 + (in >> 1) * 128 + wn * 32 + (in & 1) * 16 + lr;
        C[(size_t)grow * HH + gcol] = f2b(acc[im][in][r]);
      }
}

// ---------------------------------------------------------------------------
// k_mlp (R5-proven): per block (512 thr, 128 rows):
//   phase 1: h2[128][256] = gelu(Q @ W1^T + b1) -> LDS (swizzled [4][128][64])
//   phase 2: 8 n-tiles: out = Q + h2l @ W2^T + b2 (fp32 store)
// ---------------------------------------------------------------------------
__global__ __launch_bounds__(512, 2) void k_mlp(
    const u16* __restrict__ Qb, const u16* __restrict__ W1b,
    const u16* __restrict__ W2b, const float* __restrict__ b1,
    const float* __restrict__ b2, float* __restrict__ out)
{
  __shared__ u16 smA[128 * 64];
  __shared__ u16 smB[256 * 64];
  __shared__ u16 h2l[4][128 * 64];
  const int tid  = threadIdx.x;
  const int m0   = blockIdx.x * 128;
  const int lane = tid & 63, w = tid >> 6;      // 8 waves
  const int wm = w >> 2, wn = w & 3;            // 2M x 4N wave grid
  const int lr = lane & 15, lg = lane >> 4;
  const int srow = lane >> 3, sblk = lane & 7;

  // ---------------- phase 1: h2 = gelu(Q @ W1^T + b1) ----------------
  f32x4 acc[4][4];
  #pragma unroll
  for (int i = 0; i < 4; ++i)
    #pragma unroll
    for (int j = 0; j < 4; ++j) { f32x4 z = {0.f, 0.f, 0.f, 0.f}; acc[i][j] = z; }

  const u16* Aq = Qb + (size_t)m0 * HH;
  for (int k0 = 0; k0 < HH; k0 += 64) {
    {
      const int r  = w * 8 + srow;              // 0..63
      const int c1 = sblk ^ (r & 7);
      gload16(Aq + (size_t)r * HH + k0 + c1 * 8, smA + (w * 8) * 64);
      const int r2 = r + 64;
      const int c2 = sblk ^ (r2 & 7);
      gload16(Aq + (size_t)r2 * HH + k0 + c2 * 8, smA + (64 + w * 8) * 64);
      #pragma unroll
      for (int j = 0; j < 4; ++j) {
        const int rb = j * 64 + r;
        const int cbb = sblk ^ (rb & 7);
        gload16(W1b + (size_t)rb * HH + k0 + cbb * 8, smB + (j * 64 + w * 8) * 64);
      }
    }
    __syncthreads();
    #pragma unroll
    for (int kc = 0; kc < 2; ++kc) {
      const int blk = kc * 4 + lg;
      bf16x8 af[4], bg[4];
      #pragma unroll
      for (int mi = 0; mi < 4; ++mi) {
        const int row = wm * 64 + mi * 16 + lr;
        af[mi] = *(const bf16x8*)&smA[row * 64 + ((blk ^ (row & 7)) << 3)];
      }
      #pragma unroll
      for (int ni = 0; ni < 4; ++ni) {
        const int row = wn * 64 + ni * 16 + lr;
        bg[ni] = *(const bf16x8*)&smB[row * 64 + ((blk ^ (row & 7)) << 3)];
      }
      #pragma unroll
      for (int mi = 0; mi < 4; ++mi)
        #pragma unroll
        for (int ni = 0; ni < 4; ++ni)
          acc[mi][ni] = __builtin_amdgcn_mfma_f32_16x16x32_bf16(
              af[mi], bg[ni], acc[mi][ni], 0, 0, 0);
    }
    __syncthreads();
  }

  #pragma unroll
  for (int mi = 0; mi < 4; ++mi)
    #pragma unroll
    for (int ni = 0; ni < 4; ++ni)
      #pragma unroll
      for (int r = 0; r < 4; ++r) {
        const int row = wm * 64 + mi * 16 + lg * 4 + r;
        const int c   = wn * 64 + ni * 16 + lr;
        const float a = acc[mi][ni][r] + b1[c];
        const float cdf = 0.5f * (1.0f + erff(a * 0.70710678118654752f));
        h2l[wn][row * 64 + (((ni * 2 + (lr >> 3)) ^ (row & 7)) << 3) + (lr & 7)]
            = f2b(a * cdf);
      }
  __syncthreads();

  // ---------------- phase 2: out = Q + h2 @ W2^T + b2 ----------------
  for (int n1 = 0; n1 < 8; ++n1) {
    f32x4 acc2[4][2];
    #pragma unroll
    for (int i = 0; i < 4; ++i)
      #pragma unroll
      for (int j = 0; j < 2; ++j) { f32x4 z = {0.f, 0.f, 0.f, 0.f}; acc2[i][j] = z; }

    for (int ks = 0; ks < 4; ++ks) {
      {
        const int r  = w * 8 + srow;
        const int c1 = sblk ^ (r & 7);
        gload16(W2b + (size_t)(n1 * 128 + r) * H4 + ks * 64 + c1 * 8,
                smA + (w * 8) * 64);
        const int r2 = r + 64;
        const int c2 = sblk ^ (r2 & 7);
        gload16(W2b + (size_t)(n1 * 128 + r2) * H4 + ks * 64 + c2 * 8,
                smA + (64 + w * 8) * 64);
      }
      __syncthreads();
      #pragma unroll
      for (int kc = 0; kc < 2; ++kc) {
        const int blk = kc * 4 + lg;
        bf16x8 af[4], bg[2];
        #pragma unroll
        for (int mi = 0; mi < 4; ++mi) {
          const int row = wm * 64 + mi * 16 + lr;
          af[mi] = *(const bf16x8*)&h2l[ks][row * 64 + ((blk ^ (row & 7)) << 3)];
        }
        #pragma unroll
        for (int ni = 0; ni < 2; ++ni) {
          const int row = wn * 32 + ni * 16 + lr;
          bg[ni] = *(const bf16x8*)&smA[row * 64 + ((blk ^ (row & 7)) << 3)];
        }
        #pragma unroll
        for (int mi = 0; mi < 4; ++mi)
          #pragma unroll
          for (int ni = 0; ni < 2; ++ni)
            acc2[mi][ni] = __builtin_amdgcn_mfma_f32_16x16x32_bf16(
                af[mi], bg[ni], acc2[mi][ni], 0, 0, 0);
      }
      __syncthreads();
    }

    #pragma unroll
    for (int mi = 0; mi < 4; ++mi)
      #pragma unroll
      for (int ni = 0; ni < 2; ++ni)
        #pragma unroll
        for (int r = 0; r < 4; ++r) {
          const int grow = m0 + wm * 64 + mi * 16 + lg * 4 + r;
          const int gcol = n1 * 128 + wn * 32 + ni * 16 + lr;
          const size_t idx = (size_t)grow * HH + gcol;
          out[idx] = b2f(Qb[idx]) + acc2[mi][ni][r] + b2[gcol];
        }
  }
}

// ---------------------------------------------------------------------------
extern "C" void kernel_launch(void* const* d_in, const int* in_sizes, int n_in,
                              void* d_out, int out_size, void* d_ws, size_t ws_size,
                              hipStream_t stream)
{
  const float* in_seq = (const float*)d_in[0];
  const float* t_q = (const float*)d_in[3];
  const float* W1  = (const float*)d_in[4];
  const float* b1  = (const float*)d_in[5];
  const float* W2  = (const float*)d_in[6];
  const float* b2  = (const float*)d_in[7];
  float* out = (float*)d_out;

  char* p = (char*)d_ws;
  u16* Xb  = (u16*)p;  p += (size_t)MROWS * DD * sizeof(u16);   // 64 MiB
  u16* Qb  = (u16*)p;  p += (size_t)MROWS * HH * sizeof(u16);   // 64 MiB
  u16* Wqb = (u16*)p;  p += (size_t)HH * DD * sizeof(u16);      // 2 MiB
  u16* W1b = (u16*)p;  p += (size_t)H4 * HH * sizeof(u16);
  u16* W2b = (u16*)p;  p += (size_t)HH * H4 * sizeof(u16);

  k_cvt8<<<16384, 256, 0, stream>>>(Xb, in_seq);
  k_cvtw<<<768, 256, 0, stream>>>(t_q, W1, W2, Wqb, W1b, W2b);

  // Q = X @ t_q^T   (8-phase 256x256 counted-vmcnt, race-fixed)
  k_q8<<<dim3(128, 4), 512, 0, stream>>>(Xb, Wqb, Qb);
  // out = Q + gelu(Q@W1^T+b1)@W2^T + b2
  k_mlp<<<256, 512, 0, stream>>>(Qb, W1b, W2b, b1, b2, out);
}